// Round 1
// baseline (920.097 us; speedup 1.0000x reference)
//
#include <hip/hip_runtime.h>

#define NN 100000
#define NNZV 1600000
#define EE 1000000

typedef __attribute__((ext_vector_type(4))) float f32x4;
typedef __attribute__((ext_vector_type(8))) short bf16x8;
typedef __attribute__((ext_vector_type(8))) unsigned short us8;

__device__ __forceinline__ unsigned short f2b(float f){
  unsigned int u = __builtin_bit_cast(unsigned int, f);
  u += 0x7FFFu + ((u >> 16) & 1u);
  return (unsigned short)(u >> 16);
}
__device__ __forceinline__ float b2f(unsigned short s){
  unsigned int u = ((unsigned int)s) << 16;
  return __builtin_bit_cast(float, u);
}
__device__ __forceinline__ float ftanh(float x){
  x = fminf(15.f, fmaxf(-15.f, x));
  float e = __expf(2.f * x);
  return (e - 1.f) / (e + 1.f);
}
__device__ __forceinline__ float fsigm(float x){
  x = fminf(30.f, fmaxf(-30.f, x));
  return 1.f / (1.f + __expf(-x));
}

// XOR swizzle in 16B units within a row of RB bytes; returns ushort index.
template<int RB>
__device__ __forceinline__ int swzi(int row, int kbyte){
  constexpr int UM = (RB/16 - 1) < 15 ? (RB/16 - 1) : 15;
  int unit = (kbyte >> 4) ^ (row & UM);
  return (row*RB + (unit << 4) + (kbyte & 15)) >> 1;
}

// ---------------- CSR build ----------------
__global__ void k_hist(const int* __restrict__ row, int nnz, int* __restrict__ cnt){
  int i = blockIdx.x*blockDim.x + threadIdx.x;
  int stride = gridDim.x*blockDim.x;
  for (; i < nnz; i += stride) atomicAdd(&cnt[row[i]], 1);
}

__global__ void k_scan1(const int* __restrict__ cnt, int n, int* __restrict__ out,
                        int* __restrict__ blksum){
  __shared__ int ts[256];
  int b = blockIdx.x, t = threadIdx.x;
  int base = b*1024 + t*4;
  int v0=0,v1=0,v2=0,v3=0;
  if (base+0 < n) v0 = cnt[base+0];
  if (base+1 < n) v1 = cnt[base+1];
  if (base+2 < n) v2 = cnt[base+2];
  if (base+3 < n) v3 = cnt[base+3];
  int s = v0+v1+v2+v3;
  ts[t] = s; __syncthreads();
  for (int off=1; off<256; off<<=1){
    int x = (t >= off) ? ts[t-off] : 0;
    __syncthreads();
    ts[t] += x;
    __syncthreads();
  }
  int excl = ts[t] - s;
  if (t == 255) blksum[b] = ts[255];
  if (base+0 < n) out[base+0] = excl;
  if (base+1 < n) out[base+1] = excl+v0;
  if (base+2 < n) out[base+2] = excl+v0+v1;
  if (base+3 < n) out[base+3] = excl+v0+v1+v2;
}

__global__ void k_scan2(int* __restrict__ blksum, int nb){
  if (threadIdx.x == 0 && blockIdx.x == 0){
    int run = 0;
    for (int i = 0; i < nb; ++i){ int v = blksum[i]; blksum[i] = run; run += v; }
  }
}

__global__ void k_scan3(int* __restrict__ out, int n, const int* __restrict__ blksum, int nnz){
  int i = blockIdx.x*blockDim.x + threadIdx.x;
  if (i < n) out[i] += blksum[i >> 10];
  if (i == 0) out[n] = nnz;
}

__global__ void k_scatter(const int* __restrict__ row, const int* __restrict__ col,
                          const float* __restrict__ val, int nnz,
                          const int* __restrict__ rp, int* __restrict__ cur,
                          int* __restrict__ cs, float* __restrict__ vs){
  int i = blockIdx.x*blockDim.x + threadIdx.x;
  int stride = gridDim.x*blockDim.x;
  for (; i < nnz; i += stride){
    int r = row[i];
    int p = atomicAdd(&cur[r], 1);
    int j = rp[r] + p;
    cs[j] = col[i];
    vs[j] = val[i];
  }
}

// ---------------- h0 = tanh(x @ Wi + bi) ----------------
__global__ __launch_bounds__(256) void k_init(const float* __restrict__ x,
    const float* __restrict__ Wi, const float* __restrict__ bi,
    unsigned short* __restrict__ hb){
  __shared__ unsigned short At[64*128];
  __shared__ unsigned short Bt[64*128];
  const int t = threadIdx.x;
  const int row0 = blockIdx.x * 64;
  { // stage B: Bt[col][k] = Wi[k][col]
    int col = t & 63, kc = t >> 6;
    for (int k2 = 0; k2 < 32; ++k2){
      int k = kc*32 + k2;
      Bt[swzi<256>(col, k*2)] = f2b(Wi[k*64 + col]);
    }
  }
  { // stage A: x rows (bf16)
    int r = t >> 2, q = t & 3;
    int rr = row0 + r; if (rr >= NN) rr = NN - 1;
    const float* xp = x + (size_t)rr*128 + q*32;
    for (int j = 0; j < 4; ++j){
      float4 a = *(const float4*)(xp + j*8);
      float4 b = *(const float4*)(xp + j*8 + 4);
      us8 v;
      v[0]=f2b(a.x); v[1]=f2b(a.y); v[2]=f2b(a.z); v[3]=f2b(a.w);
      v[4]=f2b(b.x); v[5]=f2b(b.y); v[6]=f2b(b.z); v[7]=f2b(b.w);
      *(us8*)&At[swzi<256>(r, q*64 + j*16)] = v;
    }
  }
  __syncthreads();
  const int lane = t & 63, w = t >> 6, g = lane >> 4, r16 = lane & 15;
  f32x4 zv = {0.f,0.f,0.f,0.f};
  f32x4 acc[4] = {zv, zv, zv, zv};
  #pragma unroll
  for (int it = 0; it < 4; ++it){
    int kb = it*32 + g*8;
    bf16x8 a = *(bf16x8*)&At[swzi<256>(w*16 + r16, kb*2)];
    #pragma unroll
    for (int nt = 0; nt < 4; ++nt){
      bf16x8 b = *(bf16x8*)&Bt[swzi<256>(nt*16 + r16, kb*2)];
      acc[nt] = __builtin_amdgcn_mfma_f32_16x16x32_bf16(a, b, acc[nt], 0, 0, 0);
    }
  }
  #pragma unroll
  for (int nt = 0; nt < 4; ++nt){
    int col = nt*16 + r16;
    float bv = bi[col];
    #pragma unroll
    for (int q = 0; q < 4; ++q){
      int row = w*16 + g*4 + q;
      if (row0 + row < NN)
        hb[(size_t)(row0+row)*64 + col] = f2b(ftanh(acc[nt][q] + bv));
    }
  }
}

// ---------------- spmm: hp/hn = A_signed @ h ----------------
__global__ __launch_bounds__(256) void k_spmm(
    const int* __restrict__ rpP, const int* __restrict__ csP, const float* __restrict__ vsP,
    const int* __restrict__ rpN, const int* __restrict__ csN, const float* __restrict__ vsN,
    const unsigned short* __restrict__ hb, float* __restrict__ hp, float* __restrict__ hn){
  int wid = blockIdx.x*4 + (threadIdx.x >> 6);
  int lane = threadIdx.x & 63;
  int isNeg = (wid >= NN);
  int r = wid - (isNeg ? NN : 0);
  if (r >= NN) return;
  const int*   rp = isNeg ? rpN : rpP;
  const int*   cs = isNeg ? csN : csP;
  const float* vs = isNeg ? vsN : vsP;
  int s = rp[r], e = rp[r+1];
  float acc = 0.f;
  for (int base = s; base < e; base += 64){
    int idx = base + lane;
    int cR = 0; float vR = 0.f;
    if (idx < e){ cR = cs[idx]; vR = vs[idx]; }
    int cnt = min(64, e - base);
    for (int j = 0; j < cnt; ++j){
      int   c = __shfl(cR, j);
      float v = __shfl(vR, j);
      acc += v * b2f(hb[(size_t)c*64 + lane]);
    }
  }
  (isNeg ? hn : hp)[(size_t)r*64 + lane] = acc;
}

// ---------------- gate + combine + out GEMM (one hop) ----------------
__global__ __launch_bounds__(256) void k_gate(const float* __restrict__ hp,
    const float* __restrict__ hn, const float* __restrict__ Wg,
    const float* __restrict__ bg, const float* __restrict__ Wo,
    const float* __restrict__ bo, unsigned short* __restrict__ hb){
  __shared__ unsigned short A1[64*128];
  __shared__ unsigned short B1[64*128];
  __shared__ unsigned short A2[64*64];
  __shared__ unsigned short B2[64*64];
  const int t = threadIdx.x;
  const int row0 = blockIdx.x * 64;
  {
    int col = t & 63, kc = t >> 6;
    for (int k2 = 0; k2 < 32; ++k2){
      int k = kc*32 + k2;
      B1[swzi<256>(col, k*2)] = f2b(Wg[k*64 + col]);
    }
    for (int k2 = 0; k2 < 16; ++k2){
      int k = kc*16 + k2;
      B2[swzi<128>(col, k*2)] = f2b(Wo[k*64 + col]);
    }
  }
  {
    int r = t >> 2, q = t & 3;
    int rr = row0 + r; if (rr >= NN) rr = NN - 1;
    const float* src = (q < 2 ? hp : hn) + (size_t)rr*64 + (q & 1)*32;
    for (int j = 0; j < 4; ++j){
      float4 a = *(const float4*)(src + j*8);
      float4 b = *(const float4*)(src + j*8 + 4);
      us8 v;
      v[0]=f2b(a.x); v[1]=f2b(a.y); v[2]=f2b(a.z); v[3]=f2b(a.w);
      v[4]=f2b(b.x); v[5]=f2b(b.y); v[6]=f2b(b.z); v[7]=f2b(b.w);
      *(us8*)&A1[swzi<256>(r, q*64 + j*16)] = v;
    }
  }
  __syncthreads();
  const int lane = t & 63, w = t >> 6, g = lane >> 4, r16 = lane & 15;
  f32x4 zv = {0.f,0.f,0.f,0.f};
  f32x4 acc[4] = {zv, zv, zv, zv};
  #pragma unroll
  for (int it = 0; it < 4; ++it){
    int kb = it*32 + g*8;
    bf16x8 a = *(bf16x8*)&A1[swzi<256>(w*16 + r16, kb*2)];
    #pragma unroll
    for (int nt = 0; nt < 4; ++nt){
      bf16x8 b = *(bf16x8*)&B1[swzi<256>(nt*16 + r16, kb*2)];
      acc[nt] = __builtin_amdgcn_mfma_f32_16x16x32_bf16(a, b, acc[nt], 0, 0, 0);
    }
  }
  // gate + combine -> A2 (rows w*16..w*16+15 written and read by same wave)
  #pragma unroll
  for (int nt = 0; nt < 4; ++nt){
    int col = nt*16 + r16;
    float bgv = bg[col];
    #pragma unroll
    for (int q = 0; q < 4; ++q){
      int row = w*16 + g*4 + q;
      float gg  = fsigm(acc[nt][q] + bgv);
      float hpv = b2f(A1[swzi<256>(row, col*2)]);
      float hnv = b2f(A1[swzi<256>(row, (64+col)*2)]);
      A2[swzi<128>(row, col*2)] = f2b(gg*hpv + (1.f-gg)*hnv);
    }
  }
  f32x4 acc2[4] = {zv, zv, zv, zv};
  #pragma unroll
  for (int it = 0; it < 2; ++it){
    int kb = it*32 + g*8;
    bf16x8 a = *(bf16x8*)&A2[swzi<128>(w*16 + r16, kb*2)];
    #pragma unroll
    for (int nt = 0; nt < 4; ++nt){
      bf16x8 b = *(bf16x8*)&B2[swzi<128>(nt*16 + r16, kb*2)];
      acc2[nt] = __builtin_amdgcn_mfma_f32_16x16x32_bf16(a, b, acc2[nt], 0, 0, 0);
    }
  }
  #pragma unroll
  for (int nt = 0; nt < 4; ++nt){
    int col = nt*16 + r16;
    float bv = bo[col];
    #pragma unroll
    for (int q = 0; q < 4; ++q){
      int row = w*16 + g*4 + q;
      if (row0 + row < NN)
        hb[(size_t)(row0+row)*64 + col] = f2b(ftanh(acc2[nt][q] + bv));
    }
  }
}

// ---------------- edge MLP ----------------
__global__ __launch_bounds__(256) void k_edge(const int* __restrict__ ei,
    const unsigned short* __restrict__ hb, const float* __restrict__ We1,
    const float* __restrict__ be1, const float* __restrict__ We2,
    const float* __restrict__ be2, float* __restrict__ out){
  __shared__ unsigned short At[64*256];
  __shared__ unsigned short Bt[64*256];
  const int t = threadIdx.x;
  { // stage B once: Bt[col][k] = We1[k][col]
    int col = t & 63, kc = t >> 6;
    for (int k2 = 0; k2 < 64; ++k2){
      int k = kc*64 + k2;
      Bt[swzi<512>(col, k*2)] = f2b(We1[k*64 + col]);
    }
  }
  __syncthreads();
  const int lane = t & 63, w = t >> 6, g = lane >> 4, r16 = lane & 15;
  const float be2v = be2[0];
  for (int tile = blockIdx.x; tile < EE/64; tile += gridDim.x){
    int e0 = tile * 64;
    {
      int r = t >> 2, q = t & 3;
      int e = e0 + r;
      int u = ei[e], v = ei[EE + e];
      us8 hu0 = *(const us8*)&hb[(size_t)u*64 + q*16];
      us8 hu1 = *(const us8*)&hb[(size_t)u*64 + q*16 + 8];
      us8 hv0 = *(const us8*)&hb[(size_t)v*64 + q*16];
      us8 hv1 = *(const us8*)&hb[(size_t)v*64 + q*16 + 8];
      *(us8*)&At[swzi<512>(r, q*32)]        = hu0;
      *(us8*)&At[swzi<512>(r, q*32 + 16)]   = hu1;
      *(us8*)&At[swzi<512>(r, 128 + q*32)]      = hv0;
      *(us8*)&At[swzi<512>(r, 128 + q*32 + 16)] = hv1;
      us8 d0, d1, m0, m1;
      #pragma unroll
      for (int j = 0; j < 8; ++j){
        float a0 = b2f(hu0[j]), b0 = b2f(hv0[j]);
        float a1 = b2f(hu1[j]), b1 = b2f(hv1[j]);
        d0[j] = f2b(fabsf(a0 - b0)); d1[j] = f2b(fabsf(a1 - b1));
        m0[j] = f2b(a0 * b0);        m1[j] = f2b(a1 * b1);
      }
      *(us8*)&At[swzi<512>(r, 256 + q*32)]      = d0;
      *(us8*)&At[swzi<512>(r, 256 + q*32 + 16)] = d1;
      *(us8*)&At[swzi<512>(r, 384 + q*32)]      = m0;
      *(us8*)&At[swzi<512>(r, 384 + q*32 + 16)] = m1;
    }
    __syncthreads();
    f32x4 zv = {0.f,0.f,0.f,0.f};
    f32x4 acc[4] = {zv, zv, zv, zv};
    #pragma unroll
    for (int it = 0; it < 8; ++it){
      int kb = it*32 + g*8;
      bf16x8 a = *(bf16x8*)&At[swzi<512>(w*16 + r16, kb*2)];
      #pragma unroll
      for (int nt = 0; nt < 4; ++nt){
        bf16x8 b = *(bf16x8*)&Bt[swzi<512>(nt*16 + r16, kb*2)];
        acc[nt] = __builtin_amdgcn_mfma_f32_16x16x32_bf16(a, b, acc[nt], 0, 0, 0);
      }
    }
    float p0 = 0.f, p1 = 0.f, p2 = 0.f, p3 = 0.f;
    #pragma unroll
    for (int nt = 0; nt < 4; ++nt){
      int col = nt*16 + r16;
      float bb = be1[col], w2 = We2[col];
      p0 += fmaxf(acc[nt][0] + bb, 0.f) * w2;
      p1 += fmaxf(acc[nt][1] + bb, 0.f) * w2;
      p2 += fmaxf(acc[nt][2] + bb, 0.f) * w2;
      p3 += fmaxf(acc[nt][3] + bb, 0.f) * w2;
    }
    #pragma unroll
    for (int m = 1; m < 16; m <<= 1){
      p0 += __shfl_xor(p0, m);
      p1 += __shfl_xor(p1, m);
      p2 += __shfl_xor(p2, m);
      p3 += __shfl_xor(p3, m);
    }
    if (r16 == 0){
      int eb = e0 + w*16 + g*4;
      out[eb+0] = p0 + be2v;
      out[eb+1] = p1 + be2v;
      out[eb+2] = p2 + be2v;
      out[eb+3] = p3 + be2v;
    }
    __syncthreads();
  }
}

extern "C" void kernel_launch(void* const* d_in, const int* in_sizes, int n_in,
                              void* d_out, int out_size, void* d_ws, size_t ws_size,
                              hipStream_t stream){
  (void)in_sizes; (void)n_in; (void)out_size; (void)ws_size;
  const float* x       = (const float*)d_in[0];
  const int*   pos_row = (const int*)d_in[1];
  const int*   pos_col = (const int*)d_in[2];
  const float* pos_val = (const float*)d_in[3];
  const int*   neg_row = (const int*)d_in[4];
  const int*   neg_col = (const int*)d_in[5];
  const float* neg_val = (const float*)d_in[6];
  const int*   ei      = (const int*)d_in[7];
  const float* Wi      = (const float*)d_in[8];
  const float* bi      = (const float*)d_in[9];
  const float* Wg      = (const float*)d_in[10];
  const float* bg      = (const float*)d_in[11];
  const float* Wo      = (const float*)d_in[12];
  const float* bo      = (const float*)d_in[13];
  const float* We1     = (const float*)d_in[14];
  const float* be1     = (const float*)d_in[15];
  const float* We2     = (const float*)d_in[16];
  const float* be2     = (const float*)d_in[17];
  float* out = (float*)d_out;

  char* ws = (char*)d_ws;
  size_t off = 0;
  auto alloc = [&](size_t b)->char*{
    char* p = ws + off; off = (off + b + 255) & ~(size_t)255; return p;
  };
  unsigned short* hb  = (unsigned short*)alloc((size_t)NN*64*2);
  float* hp  = (float*)alloc((size_t)NN*64*4);
  float* hn  = (float*)alloc((size_t)NN*64*4);
  int*   rpP = (int*)alloc((size_t)(NN+1)*4);
  int*   rpN = (int*)alloc((size_t)(NN+1)*4);
  int*   cntP= (int*)alloc((size_t)NN*4);
  int*   cntN= (int*)alloc((size_t)NN*4);
  int*   blk = (int*)alloc(1024);
  int*   csP = (int*)alloc((size_t)NNZV*4);
  float* vsP = (float*)alloc((size_t)NNZV*4);
  int*   csN = (int*)alloc((size_t)NNZV*4);
  float* vsN = (float*)alloc((size_t)NNZV*4);

  hipMemsetAsync(cntP, 0, (size_t)NN*4, stream);
  hipMemsetAsync(cntN, 0, (size_t)NN*4, stream);
  k_hist<<<2048, 256, 0, stream>>>(pos_row, NNZV, cntP);
  k_hist<<<2048, 256, 0, stream>>>(neg_row, NNZV, cntN);
  int nb = (NN + 1023) / 1024;
  k_scan1<<<nb, 256, 0, stream>>>(cntP, NN, rpP, blk);
  k_scan2<<<1, 64, 0, stream>>>(blk, nb);
  k_scan3<<<(NN+255)/256, 256, 0, stream>>>(rpP, NN, blk, NNZV);
  k_scan1<<<nb, 256, 0, stream>>>(cntN, NN, rpN, blk);
  k_scan2<<<1, 64, 0, stream>>>(blk, nb);
  k_scan3<<<(NN+255)/256, 256, 0, stream>>>(rpN, NN, blk, NNZV);
  hipMemsetAsync(cntP, 0, (size_t)NN*4, stream);
  hipMemsetAsync(cntN, 0, (size_t)NN*4, stream);
  k_scatter<<<2048, 256, 0, stream>>>(pos_row, pos_col, pos_val, NNZV, rpP, cntP, csP, vsP);
  k_scatter<<<2048, 256, 0, stream>>>(neg_row, neg_col, neg_val, NNZV, rpN, cntN, csN, vsN);
  k_init<<<(NN+63)/64, 256, 0, stream>>>(x, Wi, bi, hb);
  for (int hop = 0; hop < 2; ++hop){
    k_spmm<<<(2*NN+3)/4, 256, 0, stream>>>(rpP, csP, vsP, rpN, csN, vsN, hb, hp, hn);
    k_gate<<<(NN+63)/64, 256, 0, stream>>>(hp, hn,
        Wg + (size_t)hop*128*64, bg + (size_t)hop*64,
        Wo + (size_t)hop*64*64,  bo + (size_t)hop*64, hb);
  }
  k_edge<<<2048, 256, 0, stream>>>(ei, hb, We1, be1, We2, be2, out);
}

// Round 2
// 690.588 us; speedup vs baseline: 1.3323x; 1.3323x over previous
//
#include <hip/hip_runtime.h>

#define NN 100000
#define NNZV 1600000
#define EE 1000000

typedef __attribute__((ext_vector_type(4))) float f32x4;
typedef __attribute__((ext_vector_type(8))) short bf16x8;
typedef __attribute__((ext_vector_type(8))) unsigned short us8;

__device__ __forceinline__ unsigned short f2b(float f){
  unsigned int u = __builtin_bit_cast(unsigned int, f);
  u += 0x7FFFu + ((u >> 16) & 1u);
  return (unsigned short)(u >> 16);
}
__device__ __forceinline__ float b2f(unsigned short s){
  unsigned int u = ((unsigned int)s) << 16;
  return __builtin_bit_cast(float, u);
}
__device__ __forceinline__ float ftanh(float x){
  x = fminf(15.f, fmaxf(-15.f, x));
  float e = __expf(2.f * x);
  return (e - 1.f) / (e + 1.f);
}
__device__ __forceinline__ float fsigm(float x){
  x = fminf(30.f, fmaxf(-30.f, x));
  return 1.f / (1.f + __expf(-x));
}

// XOR swizzle in 16B units within a row of RB bytes; returns ushort index.
template<int RB>
__device__ __forceinline__ int swzi(int row, int kbyte){
  constexpr int UM = (RB/16 - 1) < 15 ? (RB/16 - 1) : 15;
  int unit = (kbyte >> 4) ^ (row & UM);
  return (row*RB + (unit << 4) + (kbyte & 15)) >> 1;
}

// ---------------- CSR build (pos+neg merged) ----------------
__global__ void k_hist2(const int* __restrict__ rowP, const int* __restrict__ rowN,
                        int* __restrict__ cntP, int* __restrict__ cntN){
  int i = blockIdx.x*blockDim.x + threadIdx.x;
  int stride = gridDim.x*blockDim.x;
  for (; i < 2*NNZV; i += stride){
    if (i < NNZV) atomicAdd(&cntP[rowP[i]], 1);
    else          atomicAdd(&cntN[rowN[i-NNZV]], 1);
  }
}

__global__ void k_scan1(const int* __restrict__ cntP, const int* __restrict__ cntN,
                        int* __restrict__ rpP, int* __restrict__ rpN,
                        int* __restrict__ blksum, int nb){
  __shared__ int ts[256];
  int h = (blockIdx.x >= nb) ? 1 : 0;
  const int* cnt = h ? cntN : cntP;
  int* out = h ? rpN : rpP;
  int b = blockIdx.x - h*nb, t = threadIdx.x;
  int base = b*1024 + t*4;
  int v0=0,v1=0,v2=0,v3=0;
  if (base+0 < NN) v0 = cnt[base+0];
  if (base+1 < NN) v1 = cnt[base+1];
  if (base+2 < NN) v2 = cnt[base+2];
  if (base+3 < NN) v3 = cnt[base+3];
  int s = v0+v1+v2+v3;
  ts[t] = s; __syncthreads();
  for (int off=1; off<256; off<<=1){
    int x = (t >= off) ? ts[t-off] : 0;
    __syncthreads();
    ts[t] += x;
    __syncthreads();
  }
  int excl = ts[t] - s;
  if (t == 255) blksum[blockIdx.x] = ts[255];
  if (base+0 < NN) out[base+0] = excl;
  if (base+1 < NN) out[base+1] = excl+v0;
  if (base+2 < NN) out[base+2] = excl+v0+v1;
  if (base+3 < NN) out[base+3] = excl+v0+v1+v2;
}

__global__ void k_scan2(int* __restrict__ blksum, int nb){
  if (threadIdx.x == 0 && blockIdx.x == 0){
    for (int h = 0; h < 2; ++h){
      int run = 0;
      for (int i = 0; i < nb; ++i){ int v = blksum[h*nb+i]; blksum[h*nb+i] = run; run += v; }
    }
  }
}

__global__ void k_scan3(int* __restrict__ rpP, int* __restrict__ rpN,
                        const int* __restrict__ blksum, int nb){
  int i = blockIdx.x*blockDim.x + threadIdx.x;
  if (i < NN)            rpP[i] += blksum[i >> 10];
  else if (i < 2*NN)     rpN[i-NN] += blksum[nb + ((i-NN) >> 10)];
  if (i == 0){ rpP[NN] = NNZV; rpN[NN] = NNZV; }
}

// scatter using atomicSub on hist counts (no second memset / cur array)
__global__ void k_scatter2(const int* __restrict__ rowP, const int* __restrict__ colP,
                           const float* __restrict__ valP,
                           const int* __restrict__ rowN, const int* __restrict__ colN,
                           const float* __restrict__ valN,
                           const int* __restrict__ rpP, const int* __restrict__ rpN,
                           int* __restrict__ cntP, int* __restrict__ cntN,
                           int2* __restrict__ csvP, int2* __restrict__ csvN){
  int i = blockIdx.x*blockDim.x + threadIdx.x;
  int stride = gridDim.x*blockDim.x;
  for (; i < 2*NNZV; i += stride){
    if (i < NNZV){
      int r = rowP[i];
      int p = atomicSub(&cntP[r], 1) - 1;
      int2 cv; cv.x = colP[i]; cv.y = __builtin_bit_cast(int, valP[i]);
      csvP[rpP[r] + p] = cv;
    } else {
      int j = i - NNZV;
      int r = rowN[j];
      int p = atomicSub(&cntN[r], 1) - 1;
      int2 cv; cv.x = colN[j]; cv.y = __builtin_bit_cast(int, valN[j]);
      csvN[rpN[r] + p] = cv;
    }
  }
}

// ---------------- h0 = tanh(x @ Wi + bi) ----------------
__global__ __launch_bounds__(256) void k_init(const float* __restrict__ x,
    const float* __restrict__ Wi, const float* __restrict__ bi,
    unsigned short* __restrict__ hb){
  __shared__ unsigned short At[64*128];
  __shared__ unsigned short Bt[64*128];
  const int t = threadIdx.x;
  const int row0 = blockIdx.x * 64;
  {
    int col = t & 63, kc = t >> 6;
    for (int k2 = 0; k2 < 32; ++k2){
      int k = kc*32 + k2;
      Bt[swzi<256>(col, k*2)] = f2b(Wi[k*64 + col]);
    }
  }
  {
    int r = t >> 2, q = t & 3;
    int rr = row0 + r; if (rr >= NN) rr = NN - 1;
    const float* xp = x + (size_t)rr*128 + q*32;
    for (int j = 0; j < 4; ++j){
      float4 a = *(const float4*)(xp + j*8);
      float4 b = *(const float4*)(xp + j*8 + 4);
      us8 v;
      v[0]=f2b(a.x); v[1]=f2b(a.y); v[2]=f2b(a.z); v[3]=f2b(a.w);
      v[4]=f2b(b.x); v[5]=f2b(b.y); v[6]=f2b(b.z); v[7]=f2b(b.w);
      *(us8*)&At[swzi<256>(r, q*64 + j*16)] = v;
    }
  }
  __syncthreads();
  const int lane = t & 63, w = t >> 6, g = lane >> 4, r16 = lane & 15;
  f32x4 zv = {0.f,0.f,0.f,0.f};
  f32x4 acc[4] = {zv, zv, zv, zv};
  #pragma unroll
  for (int it = 0; it < 4; ++it){
    int kb = it*32 + g*8;
    bf16x8 a = *(bf16x8*)&At[swzi<256>(w*16 + r16, kb*2)];
    #pragma unroll
    for (int nt = 0; nt < 4; ++nt){
      bf16x8 b = *(bf16x8*)&Bt[swzi<256>(nt*16 + r16, kb*2)];
      acc[nt] = __builtin_amdgcn_mfma_f32_16x16x32_bf16(a, b, acc[nt], 0, 0, 0);
    }
  }
  #pragma unroll
  for (int nt = 0; nt < 4; ++nt){
    int col = nt*16 + r16;
    float bv = bi[col];
    #pragma unroll
    for (int q = 0; q < 4; ++q){
      int row = w*16 + g*4 + q;
      if (row0 + row < NN)
        hb[(size_t)(row0+row)*64 + col] = f2b(ftanh(acc[nt][q] + bv));
    }
  }
}

// ---------------- spmm: one wave per (row,sign), 4 nz/chunk ----------------
__global__ __launch_bounds__(256) void k_spmm(
    const int* __restrict__ rpP, const int2* __restrict__ csvP,
    const int* __restrict__ rpN, const int2* __restrict__ csvN,
    const unsigned short* __restrict__ hb,
    float* __restrict__ hp, float* __restrict__ hn){
  int wid = blockIdx.x*4 + (threadIdx.x >> 6);
  int lane = threadIdx.x & 63;
  int isNeg = (wid >= NN);
  int r = wid - (isNeg ? NN : 0);
  if (r >= NN) return;
  const int*  rp  = isNeg ? rpN  : rpP;
  const int2* csv = isNeg ? csvN : csvP;
  int s = rp[r], e = rp[r+1];
  const int q = lane >> 4, c = lane & 15;
  float a0=0.f, a1=0.f, a2=0.f, a3=0.f;
  int idx = s + q;
  int2 cv; cv.x = 0; cv.y = 0;
  if (idx < e) cv = csv[idx];
  for (int base = s; base < e; base += 4){
    int2 cur = cv;
    int nidx = base + 4 + q;
    cv.x = 0; cv.y = 0;
    if (nidx < e) cv = csv[nidx];               // prefetch next chunk
    float v = __builtin_bit_cast(float, cur.y);
    ushort4 hv = *(const ushort4*)&hb[(size_t)cur.x*64 + c*4];
    a0 = fmaf(v, b2f(hv.x), a0);
    a1 = fmaf(v, b2f(hv.y), a1);
    a2 = fmaf(v, b2f(hv.z), a2);
    a3 = fmaf(v, b2f(hv.w), a3);
  }
  a0 += __shfl_xor(a0, 16); a0 += __shfl_xor(a0, 32);
  a1 += __shfl_xor(a1, 16); a1 += __shfl_xor(a1, 32);
  a2 += __shfl_xor(a2, 16); a2 += __shfl_xor(a2, 32);
  a3 += __shfl_xor(a3, 16); a3 += __shfl_xor(a3, 32);
  if (q == 0){
    float4 o; o.x=a0; o.y=a1; o.z=a2; o.w=a3;
    *(float4*)&((isNeg ? hn : hp)[(size_t)r*64 + c*4]) = o;
  }
}

// ---------------- gate + combine + out GEMM (one hop) ----------------
__global__ __launch_bounds__(256) void k_gate(const float* __restrict__ hp,
    const float* __restrict__ hn, const float* __restrict__ Wg,
    const float* __restrict__ bg, const float* __restrict__ Wo,
    const float* __restrict__ bo, unsigned short* __restrict__ hb){
  __shared__ unsigned short A1[64*128];
  __shared__ unsigned short B1[64*128];
  __shared__ unsigned short A2[64*64];
  __shared__ unsigned short B2[64*64];
  const int t = threadIdx.x;
  const int row0 = blockIdx.x * 64;
  {
    int col = t & 63, kc = t >> 6;
    for (int k2 = 0; k2 < 32; ++k2){
      int k = kc*32 + k2;
      B1[swzi<256>(col, k*2)] = f2b(Wg[k*64 + col]);
    }
    for (int k2 = 0; k2 < 16; ++k2){
      int k = kc*16 + k2;
      B2[swzi<128>(col, k*2)] = f2b(Wo[k*64 + col]);
    }
  }
  {
    int r = t >> 2, q = t & 3;
    int rr = row0 + r; if (rr >= NN) rr = NN - 1;
    const float* src = (q < 2 ? hp : hn) + (size_t)rr*64 + (q & 1)*32;
    for (int j = 0; j < 4; ++j){
      float4 a = *(const float4*)(src + j*8);
      float4 b = *(const float4*)(src + j*8 + 4);
      us8 v;
      v[0]=f2b(a.x); v[1]=f2b(a.y); v[2]=f2b(a.z); v[3]=f2b(a.w);
      v[4]=f2b(b.x); v[5]=f2b(b.y); v[6]=f2b(b.z); v[7]=f2b(b.w);
      *(us8*)&A1[swzi<256>(r, q*64 + j*16)] = v;
    }
  }
  __syncthreads();
  const int lane = t & 63, w = t >> 6, g = lane >> 4, r16 = lane & 15;
  f32x4 zv = {0.f,0.f,0.f,0.f};
  f32x4 acc[4] = {zv, zv, zv, zv};
  #pragma unroll
  for (int it = 0; it < 4; ++it){
    int kb = it*32 + g*8;
    bf16x8 a = *(bf16x8*)&A1[swzi<256>(w*16 + r16, kb*2)];
    #pragma unroll
    for (int nt = 0; nt < 4; ++nt){
      bf16x8 b = *(bf16x8*)&B1[swzi<256>(nt*16 + r16, kb*2)];
      acc[nt] = __builtin_amdgcn_mfma_f32_16x16x32_bf16(a, b, acc[nt], 0, 0, 0);
    }
  }
  #pragma unroll
  for (int nt = 0; nt < 4; ++nt){
    int col = nt*16 + r16;
    float bgv = bg[col];
    #pragma unroll
    for (int q = 0; q < 4; ++q){
      int row = w*16 + g*4 + q;
      float gg  = fsigm(acc[nt][q] + bgv);
      float hpv = b2f(A1[swzi<256>(row, col*2)]);
      float hnv = b2f(A1[swzi<256>(row, (64+col)*2)]);
      A2[swzi<128>(row, col*2)] = f2b(gg*hpv + (1.f-gg)*hnv);
    }
  }
  f32x4 acc2[4] = {zv, zv, zv, zv};
  #pragma unroll
  for (int it = 0; it < 2; ++it){
    int kb = it*32 + g*8;
    bf16x8 a = *(bf16x8*)&A2[swzi<128>(w*16 + r16, kb*2)];
    #pragma unroll
    for (int nt = 0; nt < 4; ++nt){
      bf16x8 b = *(bf16x8*)&B2[swzi<128>(nt*16 + r16, kb*2)];
      acc2[nt] = __builtin_amdgcn_mfma_f32_16x16x32_bf16(a, b, acc2[nt], 0, 0, 0);
    }
  }
  #pragma unroll
  for (int nt = 0; nt < 4; ++nt){
    int col = nt*16 + r16;
    float bv = bo[col];
    #pragma unroll
    for (int q = 0; q < 4; ++q){
      int row = w*16 + g*4 + q;
      if (row0 + row < NN)
        hb[(size_t)(row0+row)*64 + col] = f2b(ftanh(acc2[nt][q] + bv));
    }
  }
}

// ---------------- edge MLP ----------------
__global__ __launch_bounds__(256) void k_edge(const int* __restrict__ ei,
    const unsigned short* __restrict__ hb, const float* __restrict__ We1,
    const float* __restrict__ be1, const float* __restrict__ We2,
    const float* __restrict__ be2, float* __restrict__ out){
  __shared__ unsigned short At[64*256];
  __shared__ unsigned short Bt[64*256];
  const int t = threadIdx.x;
  {
    int col = t & 63, kc = t >> 6;
    for (int k2 = 0; k2 < 64; ++k2){
      int k = kc*64 + k2;
      Bt[swzi<512>(col, k*2)] = f2b(We1[k*64 + col]);
    }
  }
  __syncthreads();
  const int lane = t & 63, w = t >> 6, g = lane >> 4, r16 = lane & 15;
  const float be2v = be2[0];
  for (int tile = blockIdx.x; tile < EE/64; tile += gridDim.x){
    int e0 = tile * 64;
    {
      int r = t >> 2, q = t & 3;
      int e = e0 + r;
      int u = ei[e], v = ei[EE + e];
      us8 hu0 = *(const us8*)&hb[(size_t)u*64 + q*16];
      us8 hu1 = *(const us8*)&hb[(size_t)u*64 + q*16 + 8];
      us8 hv0 = *(const us8*)&hb[(size_t)v*64 + q*16];
      us8 hv1 = *(const us8*)&hb[(size_t)v*64 + q*16 + 8];
      *(us8*)&At[swzi<512>(r, q*32)]        = hu0;
      *(us8*)&At[swzi<512>(r, q*32 + 16)]   = hu1;
      *(us8*)&At[swzi<512>(r, 128 + q*32)]      = hv0;
      *(us8*)&At[swzi<512>(r, 128 + q*32 + 16)] = hv1;
      us8 d0, d1, m0, m1;
      #pragma unroll
      for (int j = 0; j < 8; ++j){
        float a0 = b2f(hu0[j]), b0 = b2f(hv0[j]);
        float a1 = b2f(hu1[j]), b1 = b2f(hv1[j]);
        d0[j] = f2b(fabsf(a0 - b0)); d1[j] = f2b(fabsf(a1 - b1));
        m0[j] = f2b(a0 * b0);        m1[j] = f2b(a1 * b1);
      }
      *(us8*)&At[swzi<512>(r, 256 + q*32)]      = d0;
      *(us8*)&At[swzi<512>(r, 256 + q*32 + 16)] = d1;
      *(us8*)&At[swzi<512>(r, 384 + q*32)]      = m0;
      *(us8*)&At[swzi<512>(r, 384 + q*32 + 16)] = m1;
    }
    __syncthreads();
    f32x4 zv = {0.f,0.f,0.f,0.f};
    f32x4 acc[4] = {zv, zv, zv, zv};
    #pragma unroll
    for (int it = 0; it < 8; ++it){
      int kb = it*32 + g*8;
      bf16x8 a = *(bf16x8*)&At[swzi<512>(w*16 + r16, kb*2)];
      #pragma unroll
      for (int nt = 0; nt < 4; ++nt){
        bf16x8 b = *(bf16x8*)&Bt[swzi<512>(nt*16 + r16, kb*2)];
        acc[nt] = __builtin_amdgcn_mfma_f32_16x16x32_bf16(a, b, acc[nt], 0, 0, 0);
      }
    }
    float p0 = 0.f, p1 = 0.f, p2 = 0.f, p3 = 0.f;
    #pragma unroll
    for (int nt = 0; nt < 4; ++nt){
      int col = nt*16 + r16;
      float bb = be1[col], w2 = We2[col];
      p0 += fmaxf(acc[nt][0] + bb, 0.f) * w2;
      p1 += fmaxf(acc[nt][1] + bb, 0.f) * w2;
      p2 += fmaxf(acc[nt][2] + bb, 0.f) * w2;
      p3 += fmaxf(acc[nt][3] + bb, 0.f) * w2;
    }
    #pragma unroll
    for (int m = 1; m < 16; m <<= 1){
      p0 += __shfl_xor(p0, m);
      p1 += __shfl_xor(p1, m);
      p2 += __shfl_xor(p2, m);
      p3 += __shfl_xor(p3, m);
    }
    if (r16 == 0){
      int eb = e0 + w*16 + g*4;
      out[eb+0] = p0 + be2v;
      out[eb+1] = p1 + be2v;
      out[eb+2] = p2 + be2v;
      out[eb+3] = p3 + be2v;
    }
    __syncthreads();
  }
}

extern "C" void kernel_launch(void* const* d_in, const int* in_sizes, int n_in,
                              void* d_out, int out_size, void* d_ws, size_t ws_size,
                              hipStream_t stream){
  (void)in_sizes; (void)n_in; (void)out_size; (void)ws_size;
  const float* x       = (const float*)d_in[0];
  const int*   pos_row = (const int*)d_in[1];
  const int*   pos_col = (const int*)d_in[2];
  const float* pos_val = (const float*)d_in[3];
  const int*   neg_row = (const int*)d_in[4];
  const int*   neg_col = (const int*)d_in[5];
  const float* neg_val = (const float*)d_in[6];
  const int*   ei      = (const int*)d_in[7];
  const float* Wi      = (const float*)d_in[8];
  const float* bi      = (const float*)d_in[9];
  const float* Wg      = (const float*)d_in[10];
  const float* bg      = (const float*)d_in[11];
  const float* Wo      = (const float*)d_in[12];
  const float* bo      = (const float*)d_in[13];
  const float* We1     = (const float*)d_in[14];
  const float* be1     = (const float*)d_in[15];
  const float* We2     = (const float*)d_in[16];
  const float* be2     = (const float*)d_in[17];
  float* out = (float*)d_out;

  char* ws = (char*)d_ws;
  size_t off = 0;
  auto alloc = [&](size_t b)->char*{
    char* p = ws + off; off = (off + b + 255) & ~(size_t)255; return p;
  };
  unsigned short* hb = (unsigned short*)alloc((size_t)NN*64*2);
  float* hp   = (float*)alloc((size_t)NN*64*4);
  float* hn   = (float*)alloc((size_t)NN*64*4);
  int*   rpP  = (int*)alloc((size_t)(NN+1)*4);
  int*   rpN  = (int*)alloc((size_t)(NN+1)*4);
  int*   cntP = (int*)alloc((size_t)NN*4);
  int*   cntN = (int*)alloc((size_t)NN*4);
  int*   blk  = (int*)alloc(2048);
  int2*  csvP = (int2*)alloc((size_t)NNZV*8);
  int2*  csvN = (int2*)alloc((size_t)NNZV*8);

  hipMemsetAsync(cntP, 0, (size_t)NN*4, stream);
  hipMemsetAsync(cntN, 0, (size_t)NN*4, stream);
  k_hist2<<<2048, 256, 0, stream>>>(pos_row, neg_row, cntP, cntN);
  int nb = (NN + 1023) / 1024;
  k_scan1<<<2*nb, 256, 0, stream>>>(cntP, cntN, rpP, rpN, blk, nb);
  k_scan2<<<1, 64, 0, stream>>>(blk, nb);
  k_scan3<<<(2*NN+255)/256, 256, 0, stream>>>(rpP, rpN, blk, nb);
  k_scatter2<<<2048, 256, 0, stream>>>(pos_row, pos_col, pos_val,
                                       neg_row, neg_col, neg_val,
                                       rpP, rpN, cntP, cntN, csvP, csvN);
  k_init<<<(NN+63)/64, 256, 0, stream>>>(x, Wi, bi, hb);
  for (int hop = 0; hop < 2; ++hop){
    k_spmm<<<(2*NN+3)/4, 256, 0, stream>>>(rpP, csvP, rpN, csvN, hb, hp, hn);
    k_gate<<<(NN+63)/64, 256, 0, stream>>>(hp, hn,
        Wg + (size_t)hop*128*64, bg + (size_t)hop*64,
        Wo + (size_t)hop*64*64,  bo + (size_t)hop*64, hb);
  }
  k_edge<<<2048, 256, 0, stream>>>(ei, hb, We1, be1, We2, be2, out);
}